// Round 16
// baseline (1913.012 us; speedup 1.0000x reference)
//
#include <hip/hip_runtime.h>
#include <cstddef>
#include <cstdint>

constexpr int kSeq = 512;
constexpr int kH   = 256;   // hidden per direction
constexpr int kG   = 1024;  // 4*kH (gates)
constexpr int kE   = 320;   // embed dim
constexpr int kLH  = 512;   // 2*kH
constexpr int kMLP = 512;

typedef _Float16 h2 __attribute__((ext_vector_type(2)));

__device__ __forceinline__ float fexp2f(float x) {
  float r; asm("v_exp_f32 %0, %1" : "=v"(r) : "v"(x)); return r;
}
__device__ __forceinline__ float frcpf(float x) {
  float r; asm("v_rcp_f32 %0, %1" : "=v"(r) : "v"(x)); return r;
}
__device__ __forceinline__ float sigm(float x) {
  return frcpf(1.0f + fexp2f(-1.4426950408889634f * x));
}
__device__ __forceinline__ float tanh_(float x) {
  // tanh(x) = 1 - 2/(1+e^{2x}); e^{2x} = 2^(x*2*log2(e)). inf-safe at both ends.
  return 1.0f - 2.0f * frcpf(1.0f + fexp2f(2.8853900817779268f * x));
}

__device__ __forceinline__ float fdot2(unsigned int w, unsigned int h, float c) {
#if __has_builtin(__builtin_amdgcn_fdot2)
  return __builtin_amdgcn_fdot2(__builtin_bit_cast(h2, w),
                                __builtin_bit_cast(h2, h), c, false);
#else
  const h2 wv = __builtin_bit_cast(h2, w);
  const h2 hv = __builtin_bit_cast(h2, h);
  return c + (float)wv.x * (float)hv.x + (float)wv.y * (float)hv.y;
#endif
}

__device__ __forceinline__ unsigned int packh2(float a, float b) {
  h2 v; v.x = (_Float16)a; v.y = (_Float16)b;
  return __builtin_bit_cast(unsigned int, v);
}

// ---------------- embedding gather ----------------
__global__ void embed_k(const int* __restrict__ wt, const int* __restrict__ pt,
                        const float* __restrict__ we, const float* __restrict__ pe,
                        float* __restrict__ X) {
  const int t = blockIdx.x;
  const int c = threadIdx.x;  // 0..319
  const int w = wt[t];
  const int p = pt[t];
  X[t * kE + c] = (c < 256) ? we[(size_t)w * 256 + c] : pe[p * 64 + (c - 256)];
}

// ---------------- Whh f32 -> packed f16 (both layers, full GPU) ----------------
__global__ __launch_bounds__(256) void pack_wh_k(
    const float* __restrict__ whh0, const float* __restrict__ whh1,
    unsigned int* __restrict__ wh16) {
  const int idx = blockIdx.x * 256 + threadIdx.x;   // 0 .. 2*262144-1
  const int layer = idx >> 18;
  const int li = idx & 262143;
  const int rowg = li >> 7;                         // d*1024 + row
  const int c2 = li & 127;
  const float* src = (layer ? whh1 : whh0) + (size_t)rowg * kH + c2 * 2;
  wh16[idx] = packh2(src[0], src[1]);
}

// ---------------- generic f32 "NT" GEMM ----------------
template <int BM, int BN, int BK>
__global__ __launch_bounds__(256) void gemm_nt(
    const float* __restrict__ A, int lda,
    const float* __restrict__ B, int ldb,
    const float* __restrict__ b1, const float* __restrict__ b2, float scale,
    float* __restrict__ C, int csm, int csn, int K) {
  const int tid = threadIdx.x;
  const int m0 = blockIdx.y * BM;
  const int n0 = blockIdx.x * BN;
  __shared__ float As[BK][BM];
  __shared__ float Bs[BK][BN];
  const int lm = tid >> 2;
  const int lk = tid & 3;
  const int tx = tid & 15;
  const int ty = tid >> 4;
  float acc[4][4] = {};
  for (int k0 = 0; k0 < K; k0 += BK) {
    const float4 av = *(const float4*)(A + (size_t)(m0 + lm) * lda + k0 + lk * 4);
    const float4 bv = *(const float4*)(B + (size_t)(n0 + lm) * ldb + k0 + lk * 4);
    __syncthreads();
    As[lk * 4 + 0][lm] = av.x; As[lk * 4 + 1][lm] = av.y;
    As[lk * 4 + 2][lm] = av.z; As[lk * 4 + 3][lm] = av.w;
    Bs[lk * 4 + 0][lm] = bv.x; Bs[lk * 4 + 1][lm] = bv.y;
    Bs[lk * 4 + 2][lm] = bv.z; Bs[lk * 4 + 3][lm] = bv.w;
    __syncthreads();
#pragma unroll
    for (int kk = 0; kk < BK; ++kk) {
      const float4 a = *(const float4*)&As[kk][ty * 4];
      const float4 b = *(const float4*)&Bs[kk][tx * 4];
      acc[0][0] = fmaf(a.x, b.x, acc[0][0]);
      acc[0][1] = fmaf(a.x, b.y, acc[0][1]);
      acc[0][2] = fmaf(a.x, b.z, acc[0][2]);
      acc[0][3] = fmaf(a.x, b.w, acc[0][3]);
      acc[1][0] = fmaf(a.y, b.x, acc[1][0]);
      acc[1][1] = fmaf(a.y, b.y, acc[1][1]);
      acc[1][2] = fmaf(a.y, b.z, acc[1][2]);
      acc[1][3] = fmaf(a.y, b.w, acc[1][3]);
      acc[2][0] = fmaf(a.z, b.x, acc[2][0]);
      acc[2][1] = fmaf(a.z, b.y, acc[2][1]);
      acc[2][2] = fmaf(a.z, b.z, acc[2][2]);
      acc[2][3] = fmaf(a.z, b.w, acc[2][3]);
      acc[3][0] = fmaf(a.w, b.x, acc[3][0]);
      acc[3][1] = fmaf(a.w, b.y, acc[3][1]);
      acc[3][2] = fmaf(a.w, b.z, acc[3][2]);
      acc[3][3] = fmaf(a.w, b.w, acc[3][3]);
    }
  }
#pragma unroll
  for (int ii = 0; ii < 4; ++ii) {
#pragma unroll
    for (int jj = 0; jj < 4; ++jj) {
      const int m = m0 + ty * 4 + ii;
      const int n = n0 + tx * 4 + jj;
      float v = acc[ii][jj];
      if (b1) v += b1[n];
      if (b2) v += b2[n];
      C[(size_t)m * csm + (size_t)n * csn] = v * scale;
    }
  }
}

// ---------------- 2-CU-per-direction LSTM scan, role-disjoint Δ-window dot ----------------
// Workers bx {0,8} -> d=0 s=0/1, {1,9} -> d=1 (XCD co-location heuristic;
// correctness via agent-scope atomics regardless of placement).
// Wave roles (w=0..15, ch=w&1, rb=w>>1, local row r=rb*64+L):
//   ch==(1-s) waves (8): Phase A dots the REMOTE col-half of h(u-1) -> prem[r].
//     Among them: waves (1-s),(1-s)+2 = GATES; (1-s)+4,(1-s)+6 = POLLERS.
//   ch==s waves (8): no Phase A work; in Phase B they wait on an LDS flag
//     (released by gates right after h(u) own-half hits hh16), then dot the
//     OWN col-half of h(u) -> pown[(u+1)&1][r] -- INSIDE the Δ_vis window.
// Phase B: gates sum pown[u&1]+prem+pregate, update c/h, agent-publish FIRST,
// write hh16, release flag; pollers 2-deep-poll peer's h(u) into hh16.
// pown is parity-double-buffered (gates(u) read parity u&1 while own-dot(u)
// writes parity (u+1)&1 -- no race). Flag is monotonic (2/step). 2 barriers.
__global__ __launch_bounds__(1024)
__attribute__((amdgpu_waves_per_eu(4, 4)))
void lstm_scan_2cu(
    const unsigned int* __restrict__ wh16,  // (2,1024,128) packed f16 pairs
    const float* __restrict__ pre,          // (2, kSeq, kG) pregates
    float* __restrict__ out,                // (kSeq, kLH)
    float* __restrict__ comm)               // (2, kSeq, kH) f32, pre-zeroed
{
  const int bx = blockIdx.x;
  int d, s;
  if (bx == 0)      { d = 0; s = 0; }
  else if (bx == 1) { d = 1; s = 0; }
  else if (bx == 8) { d = 0; s = 1; }
  else if (bx == 9) { d = 1; s = 1; }
  else return;                         // co-location dummies exit

  const int t = threadIdx.x;
  const int w = t >> 6;
  const int L = t & 63;
  const int ch = w & 1;                 // column-half this wave's weights cover
  const int rb = w >> 1;
  const int r  = rb * 64 + L;           // local row 0..511  (= g*128 + j)
  const int g  = r >> 7;
  const int j  = r & 127;
  const int grow = g * kH + s * 128 + j;
  const bool isOwn = (ch == s);         // own-col waves: Δ-window dot

  const int wg0 = (1 - s), wg1 = (1 - s) + 2;   // gate waves (remote-col)
  const int wp0 = (1 - s) + 4, wp1 = (1 - s) + 6;  // poller waves (remote-col)
  const bool isGateWave = (w == wg0) || (w == wg1);
  const bool isPollWave = (w == wp0) || (w == wp1);
  const int ge = ((w == wg1) ? 64 : 0) + L;     // gate element 0..127
  const int e  = s * 128 + ge;                  // global h element (gates)
  const int re = (1 - s) * 128 + ((w == wp1) ? 64 : 0) + L;  // polled element

  uint4 wr[16];                         // cols [ch*128, +128) of row grow
  {
    const uint4* wp = (const uint4*)wh16 + ((size_t)d * kG + grow) * 32 + ch * 16;
#pragma unroll
    for (int k = 0; k < 16; ++k) wr[k] = wp[k];
  }

  __shared__ __align__(16) _Float16 hh16[kH];
  __shared__ float prem[512];           // remote-half partials (single buffer)
  __shared__ float pown[2][512];        // own-half partials (parity dbuf)
  __shared__ unsigned int gflag;
  if (t < 128) ((h2*)hh16)[t] = h2{(_Float16)0.f, (_Float16)0.f};
  ((float*)pown)[t] = 0.0f;             // pown[0] = 0 for u=0 (h(-1)=0)
  if (t < 512) prem[t] = 0.0f;
  if (t == 0) gflag = 0u;
  float c = 0.0f;
  __syncthreads();

  const uint4* hh4 = (const uint4*)hh16;
  float* cm = comm + (size_t)d * kSeq * kH;

  for (int u = 0; u < kSeq; ++u) {
    const int ts = d ? (kSeq - 1 - u) : u;
    // gate threads: issue pregate loads; resolve under the remote dot
    float pg0 = 0.f, pg1 = 0.f, pg2 = 0.f, pg3 = 0.f;
    if (isGateWave) {
      const float* pp = pre + ((size_t)d * kSeq + ts) * kG + e;
      pg0 = pp[0]; pg1 = pp[256]; pg2 = pp[512]; pg3 = pp[768];
    }
    // ---- Phase A: remote-col waves dot the REMOTE half of h(u-1) ----
    if (!isOwn) {
      const uint4* hp = hh4 + ch * 16;      // ch == 1-s
      float a0 = 0.f, a1 = 0.f, a2 = 0.f, a3 = 0.f;
#pragma unroll
      for (int k = 0; k < 16; ++k) {
        const uint4 hv = hp[k];             // wave-uniform LDS broadcast
        a0 = fdot2(wr[k].x, hv.x, a0);
        a1 = fdot2(wr[k].y, hv.y, a1);
        a2 = fdot2(wr[k].z, hv.z, a2);
        a3 = fdot2(wr[k].w, hv.w, a3);
      }
      prem[r] = (a0 + a1) + (a2 + a3);
    }
    __syncthreads();   // Sa: prem complete (pown[u&1] done since Sb(u-1))

    // ---- Phase B: gates || poll || own-half dot (inside Δ window) ----
    if (isGateWave) {
      const float gi = pown[u & 1][ge]        + prem[ge]        + pg0;
      const float gf = pown[u & 1][128 + ge]  + prem[128 + ge]  + pg1;
      const float gg = pown[u & 1][256 + ge]  + prem[256 + ge]  + pg2;
      const float go = pown[u & 1][384 + ge]  + prem[384 + ge]  + pg3;
      const float iv = sigm(gi), fv = sigm(gf);
      const float gv = tanh_(gg), ov = sigm(go);
      c = fv * c + iv * gv;
      const float h = ov * tanh_(c);
      __hip_atomic_store(&cm[(size_t)u * kH + e], h + 2.0f,
                         __ATOMIC_RELAXED, __HIP_MEMORY_SCOPE_AGENT);  // publish first
      hh16[e] = (_Float16)h;
      if (L == 0)  // own-half in hh16 -> release one of two tokens
        __hip_atomic_fetch_add(&gflag, 1u, __ATOMIC_RELEASE,
                               __HIP_MEMORY_SCOPE_WORKGROUP);
      out[(size_t)ts * kLH + d * kH + e] = h;
    } else if (isPollWave) {
      const float* src = &cm[(size_t)u * kH + re];
      float a = __hip_atomic_load(src, __ATOMIC_RELAXED, __HIP_MEMORY_SCOPE_AGENT);
      float b = __hip_atomic_load(src, __ATOMIC_RELAXED, __HIP_MEMORY_SCOPE_AGENT);
      while (a == 0.0f) {
        a = b;
        b = __hip_atomic_load(src, __ATOMIC_RELAXED, __HIP_MEMORY_SCOPE_AGENT);
      }
      hh16[re] = (_Float16)(a - 2.0f);
    } else if (isOwn) {
      // wait for gates' hh16 own-half, then dot it (hides under peer Δ_vis)
      const unsigned int want = 2u * (unsigned)(u + 1);
      while (__hip_atomic_load(&gflag, __ATOMIC_ACQUIRE,
                               __HIP_MEMORY_SCOPE_WORKGROUP) < want)
        __builtin_amdgcn_s_sleep(1);
      const uint4* hp = hh4 + ch * 16;      // ch == s
      float a0 = 0.f, a1 = 0.f, a2 = 0.f, a3 = 0.f;
#pragma unroll
      for (int k = 0; k < 16; ++k) {
        const uint4 hv = hp[k];
        a0 = fdot2(wr[k].x, hv.x, a0);
        a1 = fdot2(wr[k].y, hv.y, a1);
        a2 = fdot2(wr[k].z, hv.z, a2);
        a3 = fdot2(wr[k].w, hv.w, a3);
      }
      pown[(u + 1) & 1][r] = (a0 + a1) + (a2 + a3);
    }
    __syncthreads();   // Sb: hh16 = complete h(u); pown[(u+1)&1] ready
  }
}

// ---------------- pair scorer ----------------
__global__ __launch_bounds__(512) void score_k(
    const float* __restrict__ Up, const float* __restrict__ VT,
    const float* __restrict__ wout, const float* __restrict__ bout,
    float* __restrict__ out) {
  const int i = blockIdx.x;
  const int j = threadIdx.x;
  __shared__ float u_sh[kMLP];
  __shared__ float w_sh[kMLP];
  u_sh[j] = Up[(size_t)i * kMLP + j];
  w_sh[j] = wout[j];
  __syncthreads();
  float acc = 0.0f;
#pragma unroll 4
  for (int m = 0; m < kMLP; ++m) {
    const float x = u_sh[m] + VT[(size_t)m * kSeq + j];  // pre-scaled by 2*log2e
    const float th = 1.0f - 2.0f * frcpf(1.0f + fexp2f(x));
    acc = fmaf(th, w_sh[m], acc);
  }
  const float s = acc + bout[0];
  out[(size_t)i * kSeq + j] = (j == i) ? 0.0f : s;
}

extern "C" void kernel_launch(void* const* d_in, const int* in_sizes, int n_in,
                              void* d_out, int out_size, void* d_ws, size_t ws_size,
                              hipStream_t stream) {
  const int*   wt   = (const int*)d_in[0];
  const int*   pt   = (const int*)d_in[1];
  const float* wemb = (const float*)d_in[2];
  const float* pemb = (const float*)d_in[3];
  const float* wih0 = (const float*)d_in[4];
  const float* whh0 = (const float*)d_in[5];
  const float* bih0 = (const float*)d_in[6];
  const float* bhh0 = (const float*)d_in[7];
  const float* wih1 = (const float*)d_in[8];
  const float* whh1 = (const float*)d_in[9];
  const float* bih1 = (const float*)d_in[10];
  const float* bhh1 = (const float*)d_in[11];
  const float* wlin = (const float*)d_in[12];
  const float* blin = (const float*)d_in[13];
  const float* wout = (const float*)d_in[14];
  const float* bout = (const float*)d_in[15];
  float* outp = (float*)d_out;

  float* ws   = (float*)d_ws;
  float* X    = ws;                      // 512*320
  float* PG0  = X + kSeq * kE;           // 2*512*1024
  float* X1   = PG0 + 2 * kSeq * kG;     // 512*512
  float* PG1  = X1 + kSeq * kLH;         // 2*512*1024
  float* LOUT = PG1 + 2 * kSeq * kG;     // 512*512
  float* U    = LOUT + kSeq * kLH;       // 512*512
  float* VT   = U + kSeq * kMLP;         // 512*512
  float* COMM0 = VT + kSeq * kMLP;       // 2*512*256
  float* COMM1 = COMM0 + 2 * kSeq * kH;  // 2*512*256
  unsigned int* WH16 = (unsigned int*)(COMM1 + 2 * kSeq * kH);  // 2*262144

  const float SC = 2.8853900817779268f;  // 2*log2(e), folds tanh scaling

  // zero both layers' comm buffers (data-as-flag; fresh slot per step)
  hipMemsetAsync(COMM0, 0, 2 * 2 * kSeq * kH * sizeof(float), stream);

  embed_k<<<kSeq, kE, 0, stream>>>(wt, pt, wemb, pemb, X);
  pack_wh_k<<<2048, 256, 0, stream>>>(whh0, whh1, WH16);

  for (int d = 0; d < 2; ++d) {
    gemm_nt<64, 64, 16><<<dim3(kG / 64, kSeq / 64), 256, 0, stream>>>(
        X, kE, wih0 + (size_t)d * kG * kE, kE,
        bih0 + d * kG, bhh0 + d * kG, 1.0f,
        PG0 + (size_t)d * kSeq * kG, kG, 1, kE);
  }
  lstm_scan_2cu<<<10, 1024, 0, stream>>>(WH16, PG0, X1, COMM0);

  for (int d = 0; d < 2; ++d) {
    gemm_nt<64, 64, 16><<<dim3(kG / 64, kSeq / 64), 256, 0, stream>>>(
        X1, kLH, wih1 + (size_t)d * kG * kLH, kLH,
        bih1 + d * kG, bhh1 + d * kG, 1.0f,
        PG1 + (size_t)d * kSeq * kG, kG, 1, kLH);
  }
  lstm_scan_2cu<<<10, 1024, 0, stream>>>(WH16 + 2 * kG * 128, PG1, LOUT, COMM1);

  gemm_nt<64, 64, 16><<<dim3(kMLP / 64, kSeq / 64), 256, 0, stream>>>(
      LOUT, kLH, wlin, 2 * kLH, nullptr, nullptr, SC,
      U, kMLP, 1, kLH);
  gemm_nt<64, 64, 16><<<dim3(kMLP / 64, kSeq / 64), 256, 0, stream>>>(
      LOUT, kLH, wlin + kLH, 2 * kLH, blin, nullptr, SC,
      VT, 1, kSeq, kLH);

  score_k<<<kSeq, 512, 0, stream>>>(U, VT, wout, bout, outp);
}

// Round 17
// 1624.428 us; speedup vs baseline: 1.1777x; 1.1777x over previous
//
#include <hip/hip_runtime.h>
#include <cstddef>
#include <cstdint>

constexpr int kSeq = 512;
constexpr int kH   = 256;   // hidden per direction
constexpr int kG   = 1024;  // 4*kH (gates)
constexpr int kE   = 320;   // embed dim
constexpr int kLH  = 512;   // 2*kH
constexpr int kMLP = 512;

typedef _Float16 h2 __attribute__((ext_vector_type(2)));

__device__ __forceinline__ float fexp2f(float x) {
  float r; asm("v_exp_f32 %0, %1" : "=v"(r) : "v"(x)); return r;
}
__device__ __forceinline__ float frcpf(float x) {
  float r; asm("v_rcp_f32 %0, %1" : "=v"(r) : "v"(x)); return r;
}
__device__ __forceinline__ float sigm(float x) {
  return frcpf(1.0f + fexp2f(-1.4426950408889634f * x));
}
__device__ __forceinline__ float tanh_(float x) {
  // tanh(x) = 1 - 2/(1+e^{2x}); e^{2x} = 2^(x*2*log2(e)). inf-safe at both ends.
  return 1.0f - 2.0f * frcpf(1.0f + fexp2f(2.8853900817779268f * x));
}

__device__ __forceinline__ float fdot2(unsigned int w, unsigned int h, float c) {
#if __has_builtin(__builtin_amdgcn_fdot2)
  return __builtin_amdgcn_fdot2(__builtin_bit_cast(h2, w),
                                __builtin_bit_cast(h2, h), c, false);
#else
  const h2 wv = __builtin_bit_cast(h2, w);
  const h2 hv = __builtin_bit_cast(h2, h);
  return c + (float)wv.x * (float)hv.x + (float)wv.y * (float)hv.y;
#endif
}

__device__ __forceinline__ unsigned int packh2(float a, float b) {
  h2 v; v.x = (_Float16)a; v.y = (_Float16)b;
  return __builtin_bit_cast(unsigned int, v);
}

// ---------------- embedding gather ----------------
__global__ void embed_k(const int* __restrict__ wt, const int* __restrict__ pt,
                        const float* __restrict__ we, const float* __restrict__ pe,
                        float* __restrict__ X) {
  const int t = blockIdx.x;
  const int c = threadIdx.x;  // 0..319
  const int w = wt[t];
  const int p = pt[t];
  X[t * kE + c] = (c < 256) ? we[(size_t)w * 256 + c] : pe[p * 64 + (c - 256)];
}

// ---------------- Whh f32 -> packed f16 (both layers, full GPU) ----------------
// wh16[layer*262144 + (d*1024 + row)*128 + c2] = pack(col 2*c2, col 2*c2+1)
__global__ __launch_bounds__(256) void pack_wh_k(
    const float* __restrict__ whh0, const float* __restrict__ whh1,
    unsigned int* __restrict__ wh16) {
  const int idx = blockIdx.x * 256 + threadIdx.x;   // 0 .. 2*262144-1
  const int layer = idx >> 18;
  const int li = idx & 262143;
  const int rowg = li >> 7;                         // d*1024 + row
  const int c2 = li & 127;
  const float* src = (layer ? whh1 : whh0) + (size_t)rowg * kH + c2 * 2;
  wh16[idx] = packh2(src[0], src[1]);
}

// ---------------- generic f32 "NT" GEMM ----------------
template <int BM, int BN, int BK>
__global__ __launch_bounds__(256) void gemm_nt(
    const float* __restrict__ A, int lda,
    const float* __restrict__ B, int ldb,
    const float* __restrict__ b1, const float* __restrict__ b2, float scale,
    float* __restrict__ C, int csm, int csn, int K) {
  const int tid = threadIdx.x;
  const int m0 = blockIdx.y * BM;
  const int n0 = blockIdx.x * BN;
  __shared__ float As[BK][BM];
  __shared__ float Bs[BK][BN];
  const int lm = tid >> 2;
  const int lk = tid & 3;
  const int tx = tid & 15;
  const int ty = tid >> 4;
  float acc[4][4] = {};
  for (int k0 = 0; k0 < K; k0 += BK) {
    const float4 av = *(const float4*)(A + (size_t)(m0 + lm) * lda + k0 + lk * 4);
    const float4 bv = *(const float4*)(B + (size_t)(n0 + lm) * ldb + k0 + lk * 4);
    __syncthreads();
    As[lk * 4 + 0][lm] = av.x; As[lk * 4 + 1][lm] = av.y;
    As[lk * 4 + 2][lm] = av.z; As[lk * 4 + 3][lm] = av.w;
    Bs[lk * 4 + 0][lm] = bv.x; Bs[lk * 4 + 1][lm] = bv.y;
    Bs[lk * 4 + 2][lm] = bv.z; Bs[lk * 4 + 3][lm] = bv.w;
    __syncthreads();
#pragma unroll
    for (int kk = 0; kk < BK; ++kk) {
      const float4 a = *(const float4*)&As[kk][ty * 4];
      const float4 b = *(const float4*)&Bs[kk][tx * 4];
      acc[0][0] = fmaf(a.x, b.x, acc[0][0]);
      acc[0][1] = fmaf(a.x, b.y, acc[0][1]);
      acc[0][2] = fmaf(a.x, b.z, acc[0][2]);
      acc[0][3] = fmaf(a.x, b.w, acc[0][3]);
      acc[1][0] = fmaf(a.y, b.x, acc[1][0]);
      acc[1][1] = fmaf(a.y, b.y, acc[1][1]);
      acc[1][2] = fmaf(a.y, b.z, acc[1][2]);
      acc[1][3] = fmaf(a.y, b.w, acc[1][3]);
      acc[2][0] = fmaf(a.z, b.x, acc[2][0]);
      acc[2][1] = fmaf(a.z, b.y, acc[2][1]);
      acc[2][2] = fmaf(a.z, b.z, acc[2][2]);
      acc[2][3] = fmaf(a.z, b.w, acc[2][3]);
      acc[3][0] = fmaf(a.w, b.x, acc[3][0]);
      acc[3][1] = fmaf(a.w, b.y, acc[3][1]);
      acc[3][2] = fmaf(a.w, b.z, acc[3][2]);
      acc[3][3] = fmaf(a.w, b.w, acc[3][3]);
    }
  }
#pragma unroll
  for (int ii = 0; ii < 4; ++ii) {
#pragma unroll
    for (int jj = 0; jj < 4; ++jj) {
      const int m = m0 + ty * 4 + ii;
      const int n = n0 + tx * 4 + jj;
      float v = acc[ii][jj];
      if (b1) v += b1[n];
      if (b2) v += b2[n];
      C[(size_t)m * csm + (size_t)n * csn] = v * scale;
    }
  }
}

// ---------------- 2-CU-per-direction LSTM scan, poll-overlaps-production ----------------
// XCD CO-LOCATION: launch 10 blocks; assuming the m09 round-robin mapping
// (XCD = blockIdx % 8), workers bx in {0,8} (d=0, s=0/1) share XCD0 and
// bx in {1,9} (d=1) share XCD1 -> the h-exchange stays within one XCD's
// coherence neighborhood. If the mapping differs, placement is merely random
// (today's behavior); correctness is carried by agent-scope atomics.
// Per step u (2 barriers):
//   Phase A: ALL 16 waves dot their column-half of h(u-1) -> pbuf[ch][r].
//   Sa.
//   Phase B: t<128: gates, c/h update, atomic-publish h(u) own-half FIRST;
//            t in [512,640): 2-deep pipelined poll of peer's h(u)
//            (produced concurrently by the peer's Phase B).
//   Sb: hh16 = complete h(u).
// Data-as-flag: fresh slot/step, h+2.0 never 0 bits.
// NOTE (final): this is the session's best structure. Variants measured and
// rejected: sc0 L2-routing (+110%), LDS-flag Δ-window own-dot (+18-19%),
// low-contention/backoff polling (+7%), col-quarter remap (+12%). The
// residual per-step cost is the agent-scope store->load visibility round
// trip (~1600-1900 cy), overlapped with peer gate compute but not further
// reducible from HIP on this part.
__global__ __launch_bounds__(1024)
__attribute__((amdgpu_waves_per_eu(4, 4)))
void lstm_scan_2cu(
    const unsigned int* __restrict__ wh16,  // (2,1024,128) packed f16 pairs
    const float* __restrict__ pre,          // (2, kSeq, kG) pregates
    float* __restrict__ out,                // (kSeq, kLH)
    float* __restrict__ comm)               // (2, kSeq, kH) f32, pre-zeroed
{
  const int bx = blockIdx.x;
  int d, s;
  if (bx == 0)      { d = 0; s = 0; }
  else if (bx == 1) { d = 1; s = 0; }
  else if (bx == 8) { d = 0; s = 1; }
  else if (bx == 9) { d = 1; s = 1; }
  else return;                         // co-location dummies exit

  const int t = threadIdx.x;
  const int w = t >> 6;
  const int L = t & 63;
  const int ch = w & 1;                 // column-half
  const int r  = (w >> 1) * 64 + L;     // local row 0..511  (= g*128 + j)
  const int g  = r >> 7;
  const int j  = r & 127;
  const int grow = g * kH + s * 128 + j;

  uint4 wr[16];                         // cols [ch*128, +128) of row grow
  {
    const uint4* wp = (const uint4*)wh16 + ((size_t)d * kG + grow) * 32 + ch * 16;
#pragma unroll
    for (int k = 0; k < 16; ++k) wr[k] = wp[k];
  }

  __shared__ __align__(16) _Float16 hh16[kH];  // h(u-1), both halves
  __shared__ float pbuf[2][512];
  if (t < 128) ((h2*)hh16)[t] = h2{(_Float16)0.f, (_Float16)0.f};
  float c = 0.0f;
  __syncthreads();

  const uint4* hh4 = (const uint4*)hh16;
  float* cm = comm + (size_t)d * kSeq * kH;
  const bool isGate = (t < 128);
  const bool isPoll = (t >= 512 && t < 640);
  const int re = (1 - s) * 128 + (t - 512);    // element polled (valid if isPoll)

  for (int u = 0; u < kSeq; ++u) {
    const int ts = d ? (kSeq - 1 - u) : u;
    // gate threads: issue this step's 4 pregate loads; resolve under the dot
    float pg0 = 0.f, pg1 = 0.f, pg2 = 0.f, pg3 = 0.f;
    if (isGate) {
      const float* pp = pre + ((size_t)d * kSeq + ts) * kG + s * 128 + t;
      pg0 = pp[0]; pg1 = pp[256]; pg2 = pp[512]; pg3 = pp[768];
    }
    // ---- Phase A: all 16 waves dot their column-half of h(u-1) ----
    {
      const uint4* hp = hh4 + ch * 16;
      float a0 = 0.f, a1 = 0.f, a2 = 0.f, a3 = 0.f;
#pragma unroll
      for (int k = 0; k < 16; ++k) {
        const uint4 hv = hp[k];      // wave-uniform LDS broadcast
        a0 = fdot2(wr[k].x, hv.x, a0);
        a1 = fdot2(wr[k].y, hv.y, a1);
        a2 = fdot2(wr[k].z, hv.z, a2);
        a3 = fdot2(wr[k].w, hv.w, a3);
      }
      pbuf[ch][r] = (a0 + a1) + (a2 + a3);
    }
    __syncthreads();   // Sa: partials complete

    // ---- Phase B: gates (own half) || poll peer's h(u) (remote half) ----
    if (isGate) {
      const float gi = pbuf[0][t]       + pbuf[1][t]       + pg0;
      const float gf = pbuf[0][128 + t] + pbuf[1][128 + t] + pg1;
      const float gg = pbuf[0][256 + t] + pbuf[1][256 + t] + pg2;
      const float go = pbuf[0][384 + t] + pbuf[1][384 + t] + pg3;
      const float iv = sigm(gi), fv = sigm(gf);
      const float gv = tanh_(gg), ov = sigm(go);
      c = fv * c + iv * gv;
      const float h = ov * tanh_(c);
      const int e = s * 128 + t;
      __hip_atomic_store(&cm[(size_t)u * kH + e], h + 2.0f,
                         __ATOMIC_RELAXED, __HIP_MEMORY_SCOPE_AGENT);
      hh16[e] = (_Float16)h;
      out[(size_t)ts * kLH + d * kH + e] = h;
    } else if (isPoll) {
      const float* src = &cm[(size_t)u * kH + re];
      float a = __hip_atomic_load(src, __ATOMIC_RELAXED, __HIP_MEMORY_SCOPE_AGENT);
      float b = __hip_atomic_load(src, __ATOMIC_RELAXED, __HIP_MEMORY_SCOPE_AGENT);
      while (a == 0.0f) {
        a = b;
        b = __hip_atomic_load(src, __ATOMIC_RELAXED, __HIP_MEMORY_SCOPE_AGENT);
      }
      hh16[re] = (_Float16)(a - 2.0f);
    }
    __syncthreads();   // Sb: hh16 = complete h(u)
  }
}

// ---------------- pair scorer ----------------
__global__ __launch_bounds__(512) void score_k(
    const float* __restrict__ Up, const float* __restrict__ VT,
    const float* __restrict__ wout, const float* __restrict__ bout,
    float* __restrict__ out) {
  const int i = blockIdx.x;
  const int j = threadIdx.x;
  __shared__ float u_sh[kMLP];
  __shared__ float w_sh[kMLP];
  u_sh[j] = Up[(size_t)i * kMLP + j];
  w_sh[j] = wout[j];
  __syncthreads();
  float acc = 0.0f;
#pragma unroll 4
  for (int m = 0; m < kMLP; ++m) {
    const float x = u_sh[m] + VT[(size_t)m * kSeq + j];  // pre-scaled by 2*log2e
    const float th = 1.0f - 2.0f * frcpf(1.0f + fexp2f(x));
    acc = fmaf(th, w_sh[m], acc);
  }
  const float s = acc + bout[0];
  out[(size_t)i * kSeq + j] = (j == i) ? 0.0f : s;
}

extern "C" void kernel_launch(void* const* d_in, const int* in_sizes, int n_in,
                              void* d_out, int out_size, void* d_ws, size_t ws_size,
                              hipStream_t stream) {
  const int*   wt   = (const int*)d_in[0];
  const int*   pt   = (const int*)d_in[1];
  const float* wemb = (const float*)d_in[2];
  const float* pemb = (const float*)d_in[3];
  const float* wih0 = (const float*)d_in[4];
  const float* whh0 = (const float*)d_in[5];
  const float* bih0 = (const float*)d_in[6];
  const float* bhh0 = (const float*)d_in[7];
  const float* wih1 = (const float*)d_in[8];
  const float* whh1 = (const float*)d_in[9];
  const float* bih1 = (const float*)d_in[10];
  const float* bhh1 = (const float*)d_in[11];
  const float* wlin = (const float*)d_in[12];
  const float* blin = (const float*)d_in[13];
  const float* wout = (const float*)d_in[14];
  const float* bout = (const float*)d_in[15];
  float* outp = (float*)d_out;

  float* ws   = (float*)d_ws;
  float* X    = ws;                      // 512*320
  float* PG0  = X + kSeq * kE;           // 2*512*1024
  float* X1   = PG0 + 2 * kSeq * kG;     // 512*512
  float* PG1  = X1 + kSeq * kLH;         // 2*512*1024
  float* LOUT = PG1 + 2 * kSeq * kG;     // 512*512
  float* U    = LOUT + kSeq * kLH;       // 512*512
  float* VT   = U + kSeq * kMLP;         // 512*512
  float* COMM0 = VT + kSeq * kMLP;       // 2*512*256
  float* COMM1 = COMM0 + 2 * kSeq * kH;  // 2*512*256
  unsigned int* WH16 = (unsigned int*)(COMM1 + 2 * kSeq * kH);  // 2*262144

  const float SC = 2.8853900817779268f;  // 2*log2(e), folds tanh scaling

  // zero both layers' comm buffers (data-as-flag; fresh slot per step)
  hipMemsetAsync(COMM0, 0, 2 * 2 * kSeq * kH * sizeof(float), stream);

  embed_k<<<kSeq, kE, 0, stream>>>(wt, pt, wemb, pemb, X);
  pack_wh_k<<<2048, 256, 0, stream>>>(whh0, whh1, WH16);

  for (int d = 0; d < 2; ++d) {
    gemm_nt<64, 64, 16><<<dim3(kG / 64, kSeq / 64), 256, 0, stream>>>(
        X, kE, wih0 + (size_t)d * kG * kE, kE,
        bih0 + d * kG, bhh0 + d * kG, 1.0f,
        PG0 + (size_t)d * kSeq * kG, kG, 1, kE);
  }
  lstm_scan_2cu<<<10, 1024, 0, stream>>>(WH16, PG0, X1, COMM0);

  for (int d = 0; d < 2; ++d) {
    gemm_nt<64, 64, 16><<<dim3(kG / 64, kSeq / 64), 256, 0, stream>>>(
        X1, kLH, wih1 + (size_t)d * kG * kLH, kLH,
        bih1 + d * kG, bhh1 + d * kG, 1.0f,
        PG1 + (size_t)d * kSeq * kG, kG, 1, kLH);
  }
  lstm_scan_2cu<<<10, 1024, 0, stream>>>(WH16 + 2 * kG * 128, PG1, LOUT, COMM1);

  gemm_nt<64, 64, 16><<<dim3(kMLP / 64, kSeq / 64), 256, 0, stream>>>(
      LOUT, kLH, wlin, 2 * kLH, nullptr, nullptr, SC,
      U, kMLP, 1, kLH);
  gemm_nt<64, 64, 16><<<dim3(kMLP / 64, kSeq / 64), 256, 0, stream>>>(
      LOUT, kLH, wlin + kLH, 2 * kLH, blin, nullptr, SC,
      VT, 1, kSeq, kLH);

  score_k<<<kSeq, 512, 0, stream>>>(U, VT, wout, bout, outp);
}